// Round 10
// baseline (95.511 us; speedup 1.0000x reference)
//
#include <hip/hip_runtime.h>
#include <math.h>

// ---------------------------------------------------------------------------
// MutilLocalLoss on MI355X.
// Level constants (match Python int()/round() semantics exactly):
//   lev: C,  A,  CROP, TOP, OH, TJ, NTILES, CSPLIT, RSPLIT, CHUNKS, START
//   0:   64, 16,  6,    5,  11,  3,   9,     8,      1,      1,      0
//   1:   32, 32, 13,   10,  20,  5,  25,    16,      1,      1,    968
//   2:   16, 64, 26,   19,  39, 10, 100,     8,      4,      2,   4168
//   3:    8,128, 53,   38,  76, 19, 361,     8,      8,      6,  16336
// R3: prep 266µs latency-bound -> split/vectorized (311->181µs).
// R4-R7: wave supply + ILP changes; VALUBusy pinned ~24%.
// R8: 4x4 tile/thread (loads 4x down) -> 120µs; WRITE_SIZE 57MB exposed the
//     device-scope fp32 atomicAdd path as the serializer.
// R9: block-merge -> 1/4 atomics: 87µs, VALUBusy 36%. Mechanism CONFIRMED.
// R10: eliminate RMWs entirely: per-pack partial stores (exactly-once by the
//     ownership partition) + reduce kernel. Needs 3.66MB ws -> runtime branch
//     on ws_size; fallback = R9 atomic path verbatim.
// ws floats: [0,32) sc; [32,1056) prep parts; [1056,63600) corr final;
//            [63600,915008) per-pack corr partials (partial path only).
// ---------------------------------------------------------------------------

#define WS_SC 0
#define WS_PART 32
#define WS_CORR 1056
#define N_ENTRIES 62544
#define PB0 63600
#define PB1 65536
#define PB2 78336
#define PB3 175680
#define WS_NEED_BYTES 3700000

__device__ __forceinline__ float block_sum256(float v, float* sw) {
#pragma unroll
  for (int o = 32; o > 0; o >>= 1) v += __shfl_down(v, o, 64);
  if ((threadIdx.x & 63) == 0) sw[threadIdx.x >> 6] = v;
  __syncthreads();
  float r = (threadIdx.x < 4) ? sw[threadIdx.x] : 0.0f;
  r += __shfl_down(r, 2, 64);
  r += __shfl_down(r, 1, 64);
  __syncthreads();
  return r;  // total valid in thread 0
}

// ---------------- init: zero corr accumulators + out ------------------------
__global__ __launch_bounds__(256) void init_kernel(float* __restrict__ ws,
                                                   float* __restrict__ out) {
  const int e = blockIdx.x * 256 + threadIdx.x;
  if (e < N_ENTRIES) ws[WS_CORR + e] = 0.0f;
  if (e == 0) out[0] = 0.0f;
}

// ---------------- prep stage 1: 16-way sliced partial energies --------------
template <int C, int A, int CROP, int TOP>
__device__ void prep_partial_level(const float* __restrict__ grd,
                                   const float* __restrict__ sat,
                                   const float* __restrict__ mask, int b, int k,
                                   float* __restrict__ part, float* sw) {
  const float* gb = grd + (size_t)b * C * A * A;
  float s1 = 0.0f;
  constexpr int N1 = C * CROP * CROP;
  for (int idx = k * 256 + (int)threadIdx.x; idx < N1; idx += 4096) {
    int c = idx / (CROP * CROP);
    int r = idx - c * (CROP * CROP);
    int h = r / CROP;
    int w = r - h * CROP;
    float m = mask[(TOP + h) * A + (TOP + w)];
    float g = gb[((size_t)c * A + (TOP + h)) * A + (TOP + w)] * m;
    s1 += g * g;
  }
  s1 = block_sum256(s1, sw);
  const float4* sb = (const float4*)(sat + (size_t)b * C * A * A);
  const float4* m4 = (const float4*)mask;
  float s2 = 0.0f;
  constexpr int NV = C * A * A / 4;
  constexpr int MV = A * A / 4;
  for (int v = k * 256 + (int)threadIdx.x; v < NV; v += 4096) {
    float4 sv = sb[v];
    float4 mv = m4[v & (MV - 1)];
    s2 += sv.x * sv.x * mv.x + sv.y * sv.y * mv.y + sv.z * sv.z * mv.z +
          sv.w * sv.w * mv.w;
  }
  s2 = block_sum256(s2, sw);
  if (threadIdx.x == 0) {
    part[0] = s1;
    part[1] = s2;
  }
}

__global__ __launch_bounds__(256) void prep_partial_kernel(
    const float* g0, const float* s0, const float* m0, const float* g1,
    const float* s1, const float* m1, const float* g2, const float* s2,
    const float* m2, const float* g3, const float* s3, const float* m3,
    float* ws) {
  __shared__ float sw[4];
  const int pair = blockIdx.x >> 4;   // 0..31
  const int k = blockIdx.x & 15;      // slice 0..15
  const int lev = pair >> 3;
  const int b = pair & 7;
  float* part = ws + WS_PART + (pair * 16 + k) * 2;
  if (lev == 0)      prep_partial_level<64, 16, 6, 5>(g0, s0, m0, b, k, part, sw);
  else if (lev == 1) prep_partial_level<32, 32, 13, 10>(g1, s1, m1, b, k, part, sw);
  else if (lev == 2) prep_partial_level<16, 64, 26, 19>(g2, s2, m2, b, k, part, sw);
  else               prep_partial_level<8, 128, 53, 38>(g3, s3, m3, b, k, part, sw);
}

// ---------------- prep stage 2: finalize scale factors ----------------------
__global__ __launch_bounds__(64) void prep_final_kernel(float* __restrict__ ws) {
  const int t = threadIdx.x;
  if (t < 32) {
    float s1 = 0.0f, s2 = 0.0f;
    const float* p = ws + WS_PART + t * 32;
    for (int k = 0; k < 16; ++k) {
      s1 += p[2 * k];
      s2 += p[2 * k + 1];
    }
    float norm = sqrtf(s1);
    float denom = fmaxf(sqrtf(s2 + 1e-8f), 1e-6f);
    ws[WS_SC + t] = 2.0f / (fmaxf(norm, 1e-12f) * denom);
  }
}

// ---------------- corr: 4x4-tile partials, block-reduced ---------------------
// PARTIAL=true: exactly-once plain stores to per-pack region PBASE.
// PARTIAL=false: R9 behavior, 1/4-merged atomicAdd into WS_CORR.
template <bool PARTIAL, int PBASE, int C, int A, int CROP, int TOP, int OH,
          int TJ, int NTILES, int CSPLIT, int RSPLIT, int CHUNKS, int START>
__device__ void corr_level(int rel, int wv, int lane,
                           const float* __restrict__ grd,
                           const float* __restrict__ sat,
                           const float* __restrict__ mask,
                           float* __restrict__ ws, float* g_lds,
                           float* r_lds) {
  constexpr int CSP = C / CSPLIT;
  constexpr int OW = OH;
  constexpr int NV4 = (CROP + 3 + 3) / 4;  // ceil((CROP+3)/4) float4 per row
  constexpr int NPACK = CSPLIT * RSPLIT / 4;
  constexpr int E = 8 * OH * OW;  // entries in this level
  // rel -> (b, chunk, pack); wave wv covers slice pack*4+wv
  const int b = rel / (CHUNKS * NPACK);
  int r2 = rel - b * (CHUNKS * NPACK);
  const int chunk = r2 / NPACK;
  const int pack = r2 - chunk * NPACK;
  const int sl = pack * 4 + wv;
  const int cs = sl / RSPLIT;
  const int rs = sl - cs * RSPLIT;
  const int c0 = cs * CSP;
  const int r0 = (rs * CROP) / RSPLIT;       // filter-row slice [r0, r1)
  const int r1 = ((rs + 1) * CROP) / RSPLIT;
  const int nr = r1 - r0;

  // stage this wave's masked filter slice into its LDS slice (<= 371 floats)
  const float* gb = grd + (size_t)(b * C + c0) * A * A;
  for (int c = 0; c < CSP; ++c)
    for (int h = 0; h < nr; ++h)
      if (lane < CROP)
        g_lds[(c * nr + h) * CROP + lane] =
            gb[((size_t)c * A + (TOP + r0 + h)) * A + (TOP + lane)] *
            mask[(TOP + r0 + h) * A + (TOP + lane)];
  __syncthreads();

  const int s = chunk * 64 + lane;
  const bool active = s < NTILES;
  const int ss = active ? s : 0;
  const int ii = ss / TJ;
  const int jj = ss - ii * TJ;
  const int i0 = min(ii * 4, OH - 4);   // clamp; ownership masks below
  const int j0 = min(jj * 4, OW - 4);   // always 16B-aligned
  const int own_i = ii * 4 - i0;
  const int own_j = jj * 4 - j0;
  const int lastoff = min(4 * (NV4 - 1), A - 4 - j0);  // clamp final float4

  float acc[4][4] = {};
  const float* sb =
      sat + (size_t)(b * C + c0) * A * A + (size_t)(i0 + r0) * A + j0;
#pragma unroll 1
  for (int c = 0; c < CSP; ++c) {
    const float* satc = sb + (size_t)c * A * A;
    const float* gl = g_lds + c * nr * CROP;
#pragma unroll 1
    for (int r = 0; r < nr + 3; ++r) {
      // load sat row (i0+r0+r) window once; feeds up to 4 output rows
      float rbuf[NV4 * 4];
      const float* srow = satc + (size_t)r * A;
#pragma unroll
      for (int k = 0; k < NV4 - 1; ++k) {
        float4 t = *(const float4*)(srow + 4 * k);
        rbuf[4 * k + 0] = t.x;
        rbuf[4 * k + 1] = t.y;
        rbuf[4 * k + 2] = t.z;
        rbuf[4 * k + 3] = t.w;
      }
      {
        float4 t = *(const float4*)(srow + lastoff);  // clamped: may duplicate
        rbuf[4 * (NV4 - 1) + 0] = t.x;
        rbuf[4 * (NV4 - 1) + 1] = t.y;
        rbuf[4 * (NV4 - 1) + 2] = t.z;
        rbuf[4 * (NV4 - 1) + 3] = t.w;
      }
#pragma unroll
      for (int ti = 0; ti < 4; ++ti) {
        const int h = r - ti;  // filter row for output row i0+ti
        if ((unsigned)h < (unsigned)nr) {  // wave-uniform guard
          const float* grow = gl + h * CROP;
#pragma unroll
          for (int w = 0; w < CROP; ++w) {
            const float g = grow[w];
            acc[ti][0] = fmaf(rbuf[w + 0], g, acc[ti][0]);
            acc[ti][1] = fmaf(rbuf[w + 1], g, acc[ti][1]);
            acc[ti][2] = fmaf(rbuf[w + 2], g, acc[ti][2]);
            acc[ti][3] = fmaf(rbuf[w + 3], g, acc[ti][3]);
          }
        }
      }
    }
  }

  // --- block reduction: all 4 waves hold partials for the SAME tile map ---
#pragma unroll
  for (int ti = 0; ti < 4; ++ti)
#pragma unroll
    for (int tj = 0; tj < 4; ++tj)
      r_lds[((ti * 4 + tj) * 4 + wv) * 64 + lane] = acc[ti][tj];
  __syncthreads();
  // wave wv merges k = wv*4 .. wv*4+3 and emits that quarter of the outputs
#pragma unroll
  for (int kk = 0; kk < 4; ++kk) {
    const int k = wv * 4 + kk;
    const int ti = k >> 2;
    const int tj = k & 3;
    const float v = r_lds[(k * 4 + 0) * 64 + lane] +
                    r_lds[(k * 4 + 1) * 64 + lane] +
                    r_lds[(k * 4 + 2) * 64 + lane] +
                    r_lds[(k * 4 + 3) * 64 + lane];
    if (active && ti >= own_i && tj >= own_j) {
      const int addr = ((b * OH + i0 + ti) * OW) + j0 + tj;
      if constexpr (PARTIAL)
        ws[PBASE + pack * E + addr] = v;  // exactly-once plain store
      else
        atomicAdd(ws + WS_CORR + START + addr, v);
    }
  }
}

// 4 slices per 256-thread block (one per wave) of the same output chunk.
// Blocks: L0 16, L1 32, L2 128, L3 768 -> 944.
template <bool PARTIAL>
__global__ __launch_bounds__(256) void corr_kernel(
    const float* g0, const float* s0, const float* m0, const float* g1,
    const float* s1, const float* m1, const float* g2, const float* s2,
    const float* m2, const float* g3, const float* s3, const float* m3,
    float* ws) {
  __shared__ float g_lds[4 * 512];
  __shared__ float r_lds[16 * 4 * 64];
  const int wv = threadIdx.x >> 6;
  const int lane = threadIdx.x & 63;
  float* gl = g_lds + wv * 512;
  const int bid = blockIdx.x;
  if (bid < 16)
    corr_level<PARTIAL, PB0, 64, 16, 6, 5, 11, 3, 9, 8, 1, 1, 0>(
        bid, wv, lane, g0, s0, m0, ws, gl, r_lds);
  else if (bid < 48)
    corr_level<PARTIAL, PB1, 32, 32, 13, 10, 20, 5, 25, 16, 1, 1, 968>(
        bid - 16, wv, lane, g1, s1, m1, ws, gl, r_lds);
  else if (bid < 176)
    corr_level<PARTIAL, PB2, 16, 64, 26, 19, 39, 10, 100, 8, 4, 2, 4168>(
        bid - 48, wv, lane, g2, s2, m2, ws, gl, r_lds);
  else
    corr_level<PARTIAL, PB3, 8, 128, 53, 38, 76, 19, 361, 8, 8, 6, 16336>(
        bid - 176, wv, lane, g3, s3, m3, ws, gl, r_lds);
}

// ---------------- reduce: sum per-pack partials -> compact corr -------------
__global__ __launch_bounds__(256) void reduce_kernel(float* __restrict__ ws) {
  const int e = blockIdx.x * 256 + threadIdx.x;
  if (e >= N_ENTRIES) return;
  int np, base, E, r;
  if (e < 968)        { np = 2;  base = PB0; E = 968;   r = e; }
  else if (e < 4168)  { np = 4;  base = PB1; E = 3200;  r = e - 968; }
  else if (e < 16336) { np = 8;  base = PB2; E = 12168; r = e - 4168; }
  else                { np = 16; base = PB3; E = 46208; r = e - 16336; }
  float s = 0.0f;
  for (int p = 0; p < np; ++p) s += ws[base + p * E + r];
  ws[WS_CORR + e] = s;
}

// ---------------- loss: softplus contrast + scalar reduction ----------------
__global__ __launch_bounds__(256) void loss_kernel(const float* __restrict__ u,
                                                   const float* __restrict__ v,
                                                   const float* __restrict__ hd,
                                                   const float* __restrict__ ws,
                                                   float* __restrict__ out) {
  __shared__ float sw[4];
  const int e = blockIdx.x * 256 + threadIdx.x;
  float term = 0.0f;
  if (e < N_ENTRIES) {
    int lev, start, OH;
    float mpp;
    if (e < 968)        { lev = 0; start = 0;     OH = 11; mpp = 6.4f; }
    else if (e < 4168)  { lev = 1; start = 968;   OH = 20; mpp = 3.2f; }
    else if (e < 16336) { lev = 2; start = 4168;  OH = 39; mpp = 1.6f; }
    else                { lev = 3; start = 16336; OH = 76; mpp = 0.8f; }
    const int r = e - start;
    const int ow2 = OH * OH;
    const int b = r / ow2;
    const float scv = ws[WS_SC + lev * 8 + b];
    // gt position, replicating the reference fp32 op order
    float t = hd[b] * 10.0f;
    t = t / 180.0f;
    t = t * 3.14159265358979323846f;
    const float cs = cosf(t), sn = sinf(t);
    const float gdx = -u[b] * 20.0f;
    const float gdy = -v[b] * 20.0f;
    const float dxr = -gdx * cs + gdy * sn;
    const float dyr = gdx * sn + gdy * cs;
    int wi = (int)rintf(OH * 0.5f - 0.5f + dxr / mpp);  // rintf = round-half-even
    int hi = (int)rintf(OH * 0.5f - 0.5f + dyr / mpp);
    wi = min(max(wi, 0), OH - 1);
    hi = min(max(hi, 0), OH - 1);
    const float raw = ws[WS_CORR + e];
    const float rp = ws[WS_CORR + start + (b * OH + hi) * OH + wi];
    // pos - corr = sc * (raw_entry - raw_pos);  logaddexp(0, 10*(pos-corr))
    const float z = 10.0f * scv * (raw - rp);
    const float spl = fmaxf(z, 0.0f) + log1pf(expf(-fabsf(z)));
    term = spl / (8.0f * (float)(ow2 - 1));
  }
  const float tot = block_sum256(term, sw);
  if (threadIdx.x == 0) atomicAdd(out, tot);
}

// ---------------------------------------------------------------------------
extern "C" void kernel_launch(void* const* d_in, const int* in_sizes, int n_in,
                              void* d_out, int out_size, void* d_ws,
                              size_t ws_size, hipStream_t stream) {
  const float* g0 = (const float*)d_in[0];
  const float* s0 = (const float*)d_in[1];
  const float* m0 = (const float*)d_in[2];
  const float* g1 = (const float*)d_in[3];
  const float* s1 = (const float*)d_in[4];
  const float* m1 = (const float*)d_in[5];
  const float* g2 = (const float*)d_in[6];
  const float* s2 = (const float*)d_in[7];
  const float* m2 = (const float*)d_in[8];
  const float* g3 = (const float*)d_in[9];
  const float* s3 = (const float*)d_in[10];
  const float* m3 = (const float*)d_in[11];
  const float* u  = (const float*)d_in[12];
  const float* v  = (const float*)d_in[13];
  const float* hd = (const float*)d_in[14];
  float* ws = (float*)d_ws;
  float* out = (float*)d_out;
  const bool use_partial = (ws_size >= (size_t)WS_NEED_BYTES);

  init_kernel<<<dim3(245), dim3(256), 0, stream>>>(ws, out);
  prep_partial_kernel<<<dim3(512), dim3(256), 0, stream>>>(
      g0, s0, m0, g1, s1, m1, g2, s2, m2, g3, s3, m3, ws);
  prep_final_kernel<<<dim3(1), dim3(64), 0, stream>>>(ws);
  if (use_partial) {
    corr_kernel<true><<<dim3(944), dim3(256), 0, stream>>>(
        g0, s0, m0, g1, s1, m1, g2, s2, m2, g3, s3, m3, ws);
    reduce_kernel<<<dim3(245), dim3(256), 0, stream>>>(ws);
  } else {
    corr_kernel<false><<<dim3(944), dim3(256), 0, stream>>>(
        g0, s0, m0, g1, s1, m1, g2, s2, m2, g3, s3, m3, ws);
  }
  loss_kernel<<<dim3(245), dim3(256), 0, stream>>>(u, v, hd, ws, out);
}

// Round 11
// 74.792 us; speedup vs baseline: 1.2770x; 1.2770x over previous
//
#include <hip/hip_runtime.h>
#include <math.h>

// ---------------------------------------------------------------------------
// MutilLocalLoss on MI355X.
// Level constants (match Python int()/round() semantics exactly):
//   lev: C,  A,  CROP, TOP, OH, TJ8, NTILES, CSPLIT, RSPLIT, CHUNKS, START
//   0:   64, 16,  6,    5,  11,  2,    6,     8,      1,      1,      0
//   1:   32, 32, 13,   10,  20,  3,   15,    16,      1,      1,    968
//   2:   16, 64, 26,   19,  39,  5,   50,     8,      4,      1,   4168
//   3:    8,128, 53,   38,  76, 10,  190,     8,      8,      3,  16336
// R3: prep 266µs latency-bound -> split/vectorized (311->181µs).
// R4-R7: wave/ILP changes, VALUBusy pinned 24%.
// R8/R9: 4x4 tiles + block-merge -> 87µs, VALUBusy 36%.
// R10: atomics fully removed -> corr UNCHANGED 87µs: atomics exonerated.
//      Per-pipe model: 1 ds_read_b32 per 4 FMA -> LDS unit 105K cy/CU vs
//      VALU 36K -> 2.9x oversubscribed; predicted VALUBusy 34% ≈ measured 36.
// R11: cut LDS demand 8x: ds_read_b128 filter quads (padded rows RS4) and
//      4x8 output tiles (each filter value feeds 8 FMA). ds:FMA 1/4 -> 1/32.
//      Also fixed edge-quad misplacement: unclamped quads (provably in
//      bounds) + predicated scalar tail at true indices.
// ws floats: [0,32) sc; [32,1056) prep parts; [1056,63600) corr final;
//            [63600,915008) per-pack corr partials (partial path only).
// ---------------------------------------------------------------------------

#define WS_SC 0
#define WS_PART 32
#define WS_CORR 1056
#define N_ENTRIES 62544
#define PB0 63600
#define PB1 65536
#define PB2 78336
#define PB3 175680
#define WS_NEED_BYTES 3700000

__device__ __forceinline__ float block_sum256(float v, float* sw) {
#pragma unroll
  for (int o = 32; o > 0; o >>= 1) v += __shfl_down(v, o, 64);
  if ((threadIdx.x & 63) == 0) sw[threadIdx.x >> 6] = v;
  __syncthreads();
  float r = (threadIdx.x < 4) ? sw[threadIdx.x] : 0.0f;
  r += __shfl_down(r, 2, 64);
  r += __shfl_down(r, 1, 64);
  __syncthreads();
  return r;  // total valid in thread 0
}

// ---------------- init: zero corr accumulators + out ------------------------
__global__ __launch_bounds__(256) void init_kernel(float* __restrict__ ws,
                                                   float* __restrict__ out) {
  const int e = blockIdx.x * 256 + threadIdx.x;
  if (e < N_ENTRIES) ws[WS_CORR + e] = 0.0f;
  if (e == 0) out[0] = 0.0f;
}

// ---------------- prep stage 1: 16-way sliced partial energies --------------
template <int C, int A, int CROP, int TOP>
__device__ void prep_partial_level(const float* __restrict__ grd,
                                   const float* __restrict__ sat,
                                   const float* __restrict__ mask, int b, int k,
                                   float* __restrict__ part, float* sw) {
  const float* gb = grd + (size_t)b * C * A * A;
  float s1 = 0.0f;
  constexpr int N1 = C * CROP * CROP;
  for (int idx = k * 256 + (int)threadIdx.x; idx < N1; idx += 4096) {
    int c = idx / (CROP * CROP);
    int r = idx - c * (CROP * CROP);
    int h = r / CROP;
    int w = r - h * CROP;
    float m = mask[(TOP + h) * A + (TOP + w)];
    float g = gb[((size_t)c * A + (TOP + h)) * A + (TOP + w)] * m;
    s1 += g * g;
  }
  s1 = block_sum256(s1, sw);
  const float4* sb = (const float4*)(sat + (size_t)b * C * A * A);
  const float4* m4 = (const float4*)mask;
  float s2 = 0.0f;
  constexpr int NV = C * A * A / 4;
  constexpr int MV = A * A / 4;
  for (int v = k * 256 + (int)threadIdx.x; v < NV; v += 4096) {
    float4 sv = sb[v];
    float4 mv = m4[v & (MV - 1)];
    s2 += sv.x * sv.x * mv.x + sv.y * sv.y * mv.y + sv.z * sv.z * mv.z +
          sv.w * sv.w * mv.w;
  }
  s2 = block_sum256(s2, sw);
  if (threadIdx.x == 0) {
    part[0] = s1;
    part[1] = s2;
  }
}

__global__ __launch_bounds__(256) void prep_partial_kernel(
    const float* g0, const float* s0, const float* m0, const float* g1,
    const float* s1, const float* m1, const float* g2, const float* s2,
    const float* m2, const float* g3, const float* s3, const float* m3,
    float* ws) {
  __shared__ float sw[4];
  const int pair = blockIdx.x >> 4;   // 0..31
  const int k = blockIdx.x & 15;      // slice 0..15
  const int lev = pair >> 3;
  const int b = pair & 7;
  float* part = ws + WS_PART + (pair * 16 + k) * 2;
  if (lev == 0)      prep_partial_level<64, 16, 6, 5>(g0, s0, m0, b, k, part, sw);
  else if (lev == 1) prep_partial_level<32, 32, 13, 10>(g1, s1, m1, b, k, part, sw);
  else if (lev == 2) prep_partial_level<16, 64, 26, 19>(g2, s2, m2, b, k, part, sw);
  else               prep_partial_level<8, 128, 53, 38>(g3, s3, m3, b, k, part, sw);
}

// ---------------- prep stage 2: finalize scale factors ----------------------
__global__ __launch_bounds__(64) void prep_final_kernel(float* __restrict__ ws) {
  const int t = threadIdx.x;
  if (t < 32) {
    float s1 = 0.0f, s2 = 0.0f;
    const float* p = ws + WS_PART + t * 32;
    for (int k = 0; k < 16; ++k) {
      s1 += p[2 * k];
      s2 += p[2 * k + 1];
    }
    float norm = sqrtf(s1);
    float denom = fmaxf(sqrtf(s2 + 1e-8f), 1e-6f);
    ws[WS_SC + t] = 2.0f / (fmaxf(norm, 1e-12f) * denom);
  }
}

// ---------------- corr: 4x8-tile partials, b128 filter reads ----------------
// PARTIAL=true: exactly-once plain stores to per-pack region PBASE.
// PARTIAL=false: merged atomicAdd into WS_CORR (fallback, small ws).
template <bool PARTIAL, int PBASE, int C, int A, int CROP, int TOP, int OH,
          int TJ8, int NTILES, int CSPLIT, int RSPLIT, int CHUNKS, int START>
__device__ void corr_level(int rel, int wv, int lane,
                           const float* __restrict__ grd,
                           const float* __restrict__ sat,
                           const float* __restrict__ mask,
                           float* __restrict__ ws, float* g_lds,
                           float* r_lds) {
  constexpr int CSP = C / CSPLIT;
  constexpr int OW = OH;
  constexpr int RS4 = (CROP + 3) & ~3;          // padded filter row (floats)
  constexpr int NV8 = (CROP + 7 + 3) / 4;       // quads covering CROP+7 span
  constexpr int TAIL = CROP + 7 - 4 * (NV8 - 1);  // 1..4 tail elements
  constexpr int NPACK = CSPLIT * RSPLIT / 4;
  constexpr int E = 8 * OH * OW;
  // rel -> (b, chunk, pack); wave wv covers slice pack*4+wv
  const int b = rel / (CHUNKS * NPACK);
  int r2 = rel - b * (CHUNKS * NPACK);
  const int chunk = r2 / NPACK;
  const int pack = r2 - chunk * NPACK;
  const int sl = pack * 4 + wv;
  const int cs = sl / RSPLIT;
  const int rs = sl - cs * RSPLIT;
  const int c0 = cs * CSP;
  const int r0 = (rs * CROP) / RSPLIT;          // filter-row slice [r0, r1)
  const int r1 = ((rs + 1) * CROP) / RSPLIT;
  const int nr = r1 - r0;

  // stage masked filter slice, rows padded to RS4, pad zeroed (<=416 floats)
  const float* gb = grd + (size_t)(b * C + c0) * A * A;
  for (int c = 0; c < CSP; ++c)
    for (int h = 0; h < nr; ++h)
      if (lane < RS4)
        g_lds[(c * nr + h) * RS4 + lane] =
            (lane < CROP)
                ? gb[((size_t)c * A + (TOP + r0 + h)) * A + (TOP + lane)] *
                      mask[(TOP + r0 + h) * A + (TOP + lane)]
                : 0.0f;
  __syncthreads();

  const int s = chunk * 64 + lane;
  const bool active = s < NTILES;
  const int ss = active ? s : 0;
  const int ii = ss / TJ8;
  const int jj = ss - ii * TJ8;
  const int i0 = min(ii * 4, OH - 4);   // clamp; ownership masks below
  const int j0 = min(jj * 8, OW - 8);
  const int own_i = ii * 4 - i0;
  const int own_j = jj * 8 - j0;
  const int amax = A - 1 - j0;          // last valid srow index

  float acc[4][8] = {};
  const float* sb =
      sat + (size_t)(b * C + c0) * A * A + (size_t)(i0 + r0) * A + j0;
#pragma unroll 1
  for (int c = 0; c < CSP; ++c) {
    const float* satc = sb + (size_t)c * A * A;
    const float* gl = g_lds + c * nr * RS4;
#pragma unroll 1
    for (int r = 0; r < nr + 3; ++r) {
      // load sat row window once; feeds up to 4 output rows x 8 cols
      float rbuf[NV8 * 4];
      const float* srow = satc + (size_t)r * A;
#pragma unroll
      for (int k = 0; k < NV8 - 1; ++k) {  // provably in-bounds for all tiles
        float4 t = *(const float4*)(srow + 4 * k);
        rbuf[4 * k + 0] = t.x;
        rbuf[4 * k + 1] = t.y;
        rbuf[4 * k + 2] = t.z;
        rbuf[4 * k + 3] = t.w;
      }
#pragma unroll
      for (int q = 0; q < TAIL; ++q) {   // predicated tail, true positions
        const int idx = 4 * (NV8 - 1) + q;
        rbuf[idx] = (idx <= amax) ? srow[idx] : 0.0f;
      }
#pragma unroll
      for (int ti = 0; ti < 4; ++ti) {
        const int h = r - ti;  // filter row for output row i0+ti
        if ((unsigned)h < (unsigned)nr) {  // wave-uniform guard
          const float* grow = gl + h * RS4;
#pragma unroll
          for (int w4 = 0; w4 < RS4 / 4; ++w4) {
            const float4 gq = *(const float4*)(grow + 4 * w4);  // ds_read_b128
#pragma unroll
            for (int gi = 0; gi < 4; ++gi) {
              constexpr int dummy = 0; (void)dummy;
              const int w = 4 * w4 + gi;
              if (w < CROP) {  // compile-time: pad lanes dropped
                const float g = (gi == 0) ? gq.x : (gi == 1) ? gq.y
                                : (gi == 2) ? gq.z : gq.w;
#pragma unroll
                for (int tj = 0; tj < 8; ++tj)
                  acc[ti][tj] = fmaf(rbuf[w + tj], g, acc[ti][tj]);
              }
            }
          }
        }
      }
    }
  }

  // --- block reduction: 4 waves hold partials for the SAME tile map -------
  // 32 accs merged in two 16-slice passes through r_lds[16][4][64] (16KB).
#pragma unroll
  for (int p = 0; p < 2; ++p) {
    if (p) __syncthreads();
#pragma unroll
    for (int k2 = 0; k2 < 16; ++k2) {
      const int gk = p * 16 + k2;
      r_lds[(k2 * 4 + wv) * 64 + lane] = acc[gk >> 3][gk & 7];
    }
    __syncthreads();
#pragma unroll
    for (int kk = 0; kk < 4; ++kk) {
      const int k2 = wv * 4 + kk;
      const int gk = p * 16 + k2;
      const int ti = gk >> 3;
      const int tj = gk & 7;
      const float v = r_lds[(k2 * 4 + 0) * 64 + lane] +
                      r_lds[(k2 * 4 + 1) * 64 + lane] +
                      r_lds[(k2 * 4 + 2) * 64 + lane] +
                      r_lds[(k2 * 4 + 3) * 64 + lane];
      if (active && ti >= own_i && tj >= own_j) {
        const int addr = ((b * OH + i0 + ti) * OW) + j0 + tj;
        if constexpr (PARTIAL)
          ws[PBASE + pack * E + addr] = v;  // exactly-once plain store
        else
          atomicAdd(ws + WS_CORR + START + addr, v);
      }
    }
  }
}

// 4 slices per 256-thread block (one per wave) of the same output chunk.
// Blocks: L0 8*1*2=16, L1 8*1*4=32, L2 8*1*8=64, L3 8*3*16=384 -> 496.
template <bool PARTIAL>
__global__ __launch_bounds__(256) void corr_kernel(
    const float* g0, const float* s0, const float* m0, const float* g1,
    const float* s1, const float* m1, const float* g2, const float* s2,
    const float* m2, const float* g3, const float* s3, const float* m3,
    float* ws) {
  __shared__ float g_lds[4 * 416];
  __shared__ float r_lds[16 * 4 * 64];
  const int wv = threadIdx.x >> 6;
  const int lane = threadIdx.x & 63;
  float* gl = g_lds + wv * 416;
  const int bid = blockIdx.x;
  if (bid < 16)
    corr_level<PARTIAL, PB0, 64, 16, 6, 5, 11, 2, 6, 8, 1, 1, 0>(
        bid, wv, lane, g0, s0, m0, ws, gl, r_lds);
  else if (bid < 48)
    corr_level<PARTIAL, PB1, 32, 32, 13, 10, 20, 3, 15, 16, 1, 1, 968>(
        bid - 16, wv, lane, g1, s1, m1, ws, gl, r_lds);
  else if (bid < 112)
    corr_level<PARTIAL, PB2, 16, 64, 26, 19, 39, 5, 50, 8, 4, 1, 4168>(
        bid - 48, wv, lane, g2, s2, m2, ws, gl, r_lds);
  else
    corr_level<PARTIAL, PB3, 8, 128, 53, 38, 76, 10, 190, 8, 8, 3, 16336>(
        bid - 112, wv, lane, g3, s3, m3, ws, gl, r_lds);
}

// ---------------- reduce: sum per-pack partials -> compact corr -------------
__global__ __launch_bounds__(256) void reduce_kernel(float* __restrict__ ws) {
  const int e = blockIdx.x * 256 + threadIdx.x;
  if (e >= N_ENTRIES) return;
  int np, base, E, r;
  if (e < 968)        { np = 2;  base = PB0; E = 968;   r = e; }
  else if (e < 4168)  { np = 4;  base = PB1; E = 3200;  r = e - 968; }
  else if (e < 16336) { np = 8;  base = PB2; E = 12168; r = e - 4168; }
  else                { np = 16; base = PB3; E = 46208; r = e - 16336; }
  float s = 0.0f;
  for (int p = 0; p < np; ++p) s += ws[base + p * E + r];
  ws[WS_CORR + e] = s;
}

// ---------------- loss: softplus contrast + scalar reduction ----------------
__global__ __launch_bounds__(256) void loss_kernel(const float* __restrict__ u,
                                                   const float* __restrict__ v,
                                                   const float* __restrict__ hd,
                                                   const float* __restrict__ ws,
                                                   float* __restrict__ out) {
  __shared__ float sw[4];
  const int e = blockIdx.x * 256 + threadIdx.x;
  float term = 0.0f;
  if (e < N_ENTRIES) {
    int lev, start, OH;
    float mpp;
    if (e < 968)        { lev = 0; start = 0;     OH = 11; mpp = 6.4f; }
    else if (e < 4168)  { lev = 1; start = 968;   OH = 20; mpp = 3.2f; }
    else if (e < 16336) { lev = 2; start = 4168;  OH = 39; mpp = 1.6f; }
    else                { lev = 3; start = 16336; OH = 76; mpp = 0.8f; }
    const int r = e - start;
    const int ow2 = OH * OH;
    const int b = r / ow2;
    const float scv = ws[WS_SC + lev * 8 + b];
    // gt position, replicating the reference fp32 op order
    float t = hd[b] * 10.0f;
    t = t / 180.0f;
    t = t * 3.14159265358979323846f;
    const float cs = cosf(t), sn = sinf(t);
    const float gdx = -u[b] * 20.0f;
    const float gdy = -v[b] * 20.0f;
    const float dxr = -gdx * cs + gdy * sn;
    const float dyr = gdx * sn + gdy * cs;
    int wi = (int)rintf(OH * 0.5f - 0.5f + dxr / mpp);  // rintf = round-half-even
    int hi = (int)rintf(OH * 0.5f - 0.5f + dyr / mpp);
    wi = min(max(wi, 0), OH - 1);
    hi = min(max(hi, 0), OH - 1);
    const float raw = ws[WS_CORR + e];
    const float rp = ws[WS_CORR + start + (b * OH + hi) * OH + wi];
    // pos - corr = sc * (raw_entry - raw_pos);  logaddexp(0, 10*(pos-corr))
    const float z = 10.0f * scv * (raw - rp);
    const float spl = fmaxf(z, 0.0f) + log1pf(expf(-fabsf(z)));
    term = spl / (8.0f * (float)(ow2 - 1));
  }
  const float tot = block_sum256(term, sw);
  if (threadIdx.x == 0) atomicAdd(out, tot);
}

// ---------------------------------------------------------------------------
extern "C" void kernel_launch(void* const* d_in, const int* in_sizes, int n_in,
                              void* d_out, int out_size, void* d_ws,
                              size_t ws_size, hipStream_t stream) {
  const float* g0 = (const float*)d_in[0];
  const float* s0 = (const float*)d_in[1];
  const float* m0 = (const float*)d_in[2];
  const float* g1 = (const float*)d_in[3];
  const float* s1 = (const float*)d_in[4];
  const float* m1 = (const float*)d_in[5];
  const float* g2 = (const float*)d_in[6];
  const float* s2 = (const float*)d_in[7];
  const float* m2 = (const float*)d_in[8];
  const float* g3 = (const float*)d_in[9];
  const float* s3 = (const float*)d_in[10];
  const float* m3 = (const float*)d_in[11];
  const float* u  = (const float*)d_in[12];
  const float* v  = (const float*)d_in[13];
  const float* hd = (const float*)d_in[14];
  float* ws = (float*)d_ws;
  float* out = (float*)d_out;
  const bool use_partial = (ws_size >= (size_t)WS_NEED_BYTES);

  init_kernel<<<dim3(245), dim3(256), 0, stream>>>(ws, out);
  prep_partial_kernel<<<dim3(512), dim3(256), 0, stream>>>(
      g0, s0, m0, g1, s1, m1, g2, s2, m2, g3, s3, m3, ws);
  prep_final_kernel<<<dim3(1), dim3(64), 0, stream>>>(ws);
  if (use_partial) {
    corr_kernel<true><<<dim3(496), dim3(256), 0, stream>>>(
        g0, s0, m0, g1, s1, m1, g2, s2, m2, g3, s3, m3, ws);
    reduce_kernel<<<dim3(245), dim3(256), 0, stream>>>(ws);
  } else {
    corr_kernel<false><<<dim3(496), dim3(256), 0, stream>>>(
        g0, s0, m0, g1, s1, m1, g2, s2, m2, g3, s3, m3, ws);
  }
  loss_kernel<<<dim3(245), dim3(256), 0, stream>>>(u, v, hd, ws, out);
}